// Round 6
// baseline (1059.944 us; speedup 1.0000x reference)
//
#include <hip/hip_runtime.h>

typedef unsigned short u16;
typedef signed char s8;
typedef __attribute__((ext_vector_type(8))) short bf16x8;
typedef __attribute__((ext_vector_type(4))) float f32x4;
typedef __attribute__((ext_vector_type(4))) int i32x4;

__device__ __forceinline__ u16 f2bf(float x) {
  unsigned int u = __float_as_uint(x);
  u = u + 0x7FFFu + ((u >> 16) & 1u);
  return (u16)(u >> 16);
}
__device__ __forceinline__ float bf2f(u16 v) {
  return __uint_as_float(((unsigned int)v) << 16);
}

typedef const __attribute__((address_space(1))) void gas_void;
typedef __attribute__((address_space(3))) void las_void;

__device__ __forceinline__ void gld_lds16(const void* g, void* l) {
  __builtin_amdgcn_global_load_lds((gas_void*)g, (las_void*)l, 16, 0, 0);
}

// ---------------- i8 logits GEMM: S = 2*h@cb^T - c_sq via split-2 i8 ----------------
// h = h0/16 + h1/4096 + eps, cb likewise. Four exact-i32 passes:
//   M = h0@c0, X = h0@c1 + h1@c0, Y = h1@c1
//   S = M*2/256 + X*2/65536 + Y*2/16777216 - c_sq
// Block tile 128x64, 4 waves (2x2), wave tile 64x32, BK=64.
__device__ __forceinline__ void s8_ktile(const s8* __restrict__ Asrc,
                                         const s8* __restrict__ Bsrc,
                                         long bm, long bn, s8* lA, s8* lB,
                                         i32x4 (&acc)[4][2], int tid, int wave,
                                         int wm, int wn, int r15, int kg) {
  for (int k0 = 0; k0 < 1024; k0 += 64) {
    __syncthreads();
    int r = tid >> 2, cc = (tid & 3) * 16;
    // A tile [128][64] i8: rows 0-63 then 64-127
    gld_lds16(Asrc + (bm + r) * 1024 + k0 + cc, lA + wave * 1024);
    gld_lds16(Asrc + (bm + 64 + r) * 1024 + k0 + cc, lA + 4096 + wave * 1024);
    // B tile [64][64] i8
    gld_lds16(Bsrc + (bn + r) * 1024 + k0 + cc, lB + wave * 1024);
    __syncthreads();
    i32x4 a[4], b[2];
#pragma unroll
    for (int i = 0; i < 4; ++i)
      a[i] = *(const i32x4*)&lA[(wm + i * 16 + r15) * 64 + kg * 16];
#pragma unroll
    for (int j = 0; j < 2; ++j)
      b[j] = *(const i32x4*)&lB[(wn + j * 16 + r15) * 64 + kg * 16];
#pragma unroll
    for (int i = 0; i < 4; ++i)
#pragma unroll
      for (int j = 0; j < 2; ++j)
        acc[i][j] = __builtin_amdgcn_mfma_i32_16x16x64_i8(a[i], b[j], acc[i][j], 0, 0, 0);
  }
}

__global__ __launch_bounds__(256) void gemm_s8(
    const s8* __restrict__ A0, const s8* __restrict__ A1,
    const s8* __restrict__ B0, const s8* __restrict__ B1,
    float* __restrict__ S, const float* __restrict__ c_sq) {
  __shared__ __align__(16) s8 lA[128 * 64];
  __shared__ __align__(16) s8 lB[64 * 64];
  int tid = threadIdx.x, wave = tid >> 6, lane = tid & 63;
  long bm = (long)blockIdx.y * 128, bn = (long)blockIdx.x * 64;
  int wm = (wave >> 1) * 64, wn = (wave & 1) * 32;
  int r15 = lane & 15, kg = lane >> 4;

  i32x4 accM[4][2], accX[4][2], accY[4][2];
#pragma unroll
  for (int i = 0; i < 4; ++i)
#pragma unroll
    for (int j = 0; j < 2; ++j) {
      accM[i][j] = (i32x4){0, 0, 0, 0};
      accX[i][j] = (i32x4){0, 0, 0, 0};
      accY[i][j] = (i32x4){0, 0, 0, 0};
    }

  s8_ktile(A0, B0, bm, bn, lA, lB, accM, tid, wave, wm, wn, r15, kg);
  s8_ktile(A0, B1, bm, bn, lA, lB, accX, tid, wave, wm, wn, r15, kg);
  s8_ktile(A1, B0, bm, bn, lA, lB, accX, tid, wave, wm, wn, r15, kg);
  s8_ktile(A1, B1, bm, bn, lA, lB, accY, tid, wave, wm, wn, r15, kg);

  // C/D layout: col=lane&15, row=(lane>>4)*4+r
#pragma unroll
  for (int i = 0; i < 4; ++i) {
    long rg = bm + wm + i * 16 + kg * 4;
#pragma unroll
    for (int j = 0; j < 2; ++j) {
      long cg = bn + wn + j * 16 + r15;
      float csq = c_sq[cg];
      i32x4 m = accM[i][j], x = accX[i][j], y = accY[i][j];
#pragma unroll
      for (int r = 0; r < 4; ++r)
        S[(rg + r) * 8192 + cg] = (float)m[r] * 0.0078125f +
                                  (float)x[r] * 3.0517578125e-05f +
                                  (float)y[r] * 1.1920928955078125e-07f - csq;
    }
  }
}

// ---------------- bf16 GEMM (m97-style), MODES 2 (z_q) and 3 (split-K z_e) ----------------
#define BM 128
#define BN 128
#define BK 32

__device__ __forceinline__ void stage_tile(const u16* __restrict__ src, long lda,
                                           long row0, long k0, u16* ldst, int tid) {
  int wave = tid >> 6;
#pragma unroll
  for (int c = 0; c < 2; ++c) {
    int chunk = c * 256 + tid;
    int r = chunk >> 2;
    int col = (chunk & 3) * 8;
    const u16* g = src + (row0 + r) * lda + k0 + col;
    u16* l = ldst + c * 2048 + wave * 512;
    gld_lds16(g, l);
  }
}

template <int MODE>
__global__ __launch_bounds__(256) void gemm_bt(
    const u16* __restrict__ A0, long lda,
    const u16* __restrict__ B0, long ldb,
    void* __restrict__ Cv, long ldc, int KSPAN,
    const float* __restrict__ aux0, const float* __restrict__ aux1, long zstride) {
  __shared__ __align__(16) u16 lA0[BM * BK];
  __shared__ __align__(16) u16 lB0[BN * BK];

  int tid = threadIdx.x;
  int wave = tid >> 6, lane = tid & 63;
  long bm = (long)blockIdx.y * BM, bn = (long)blockIdx.x * BN;
  int wm = (wave >> 1) * 64, wn = (wave & 1) * 64;
  int r15 = lane & 15, kg = lane >> 4;
  long kbase = 0;
  if constexpr (MODE == 3) kbase = (long)blockIdx.z * KSPAN;

  f32x4 acc[4][4];
#pragma unroll
  for (int i = 0; i < 4; ++i)
#pragma unroll
    for (int j = 0; j < 4; ++j) acc[i][j] = (f32x4){0.f, 0.f, 0.f, 0.f};

  for (int k0 = 0; k0 < KSPAN; k0 += BK) {
    __syncthreads();
    stage_tile(A0, lda, bm, kbase + k0, lA0, tid);
    stage_tile(B0, ldb, bn, kbase + k0, lB0, tid);
    __syncthreads();

    bf16x8 ah[4], bh[4];
#pragma unroll
    for (int i = 0; i < 4; ++i) {
      ah[i] = *(const bf16x8*)&lA0[(wm + i * 16 + r15) * BK + kg * 8];
      bh[i] = *(const bf16x8*)&lB0[(wn + i * 16 + r15) * BK + kg * 8];
    }
#pragma unroll
    for (int i = 0; i < 4; ++i)
#pragma unroll
      for (int j = 0; j < 4; ++j)
        acc[i][j] = __builtin_amdgcn_mfma_f32_16x16x32_bf16(ah[i], bh[j], acc[i][j], 0, 0, 0);
  }

#pragma unroll
  for (int i = 0; i < 4; ++i) {
    long rg = bm + wm + i * 16 + kg * 4;
#pragma unroll
    for (int j = 0; j < 4; ++j) {
      long cg = bn + wn + j * 16 + r15;
      f32x4 v = acc[i][j];
      if constexpr (MODE == 2) {
        float* C = (float*)Cv;
        float bb = aux1[cg];
#pragma unroll
        for (int r = 0; r < 4; ++r)
          C[(rg + r) * ldc + cg] = v[r] + aux0[(rg + r) * ldc + cg] + bb;
      } else {
        u16* P = (u16*)Cv + (long)blockIdx.z * zstride;
#pragma unroll
        for (int r = 0; r < 4; ++r) P[(rg + r) * ldc + cg] = f2bf(v[r]);
      }
    }
  }
}

// ---------------- prep kernels ----------------
__device__ __forceinline__ int quant2(float x) {
  // packed (q0, q1): q0 = round(x*16) in [-127,127]; r = x - q0/16 in [-1/32,1/32];
  // q1 = round(r*4096) clipped to [-127,127]  (residual <= ~1/8192)
  float x0 = rintf(x * 16.f);
  x0 = fminf(fmaxf(x0, -127.f), 127.f);
  float x1 = rintf((x - x0 * 0.0625f) * 4096.f);
  x1 = fminf(fmaxf(x1, -127.f), 127.f);
  return ((int)x0 & 0xFF) | (((int)x1 & 0xFF) << 8);
}

__device__ __forceinline__ void quant4(float4 v, unsigned int& w0, unsigned int& w1) {
  int px = quant2(v.x), py = quant2(v.y), pz = quant2(v.z), pw = quant2(v.w);
  w0 = (unsigned int)((px & 0xFF) | ((py & 0xFF) << 8) | ((pz & 0xFF) << 16) |
                      ((pw & 0xFF) << 24));
  w1 = (unsigned int)(((px >> 8) & 0xFF) | (((py >> 8) & 0xFF) << 8) |
                      (((pz >> 8) & 0xFF) << 16) | (((pw >> 8) & 0xFF) << 24));
}

__global__ __launch_bounds__(256) void prep_h_i8(const float* __restrict__ in,
                                                 s8* __restrict__ q0, s8* __restrict__ q1,
                                                 int n4) {
  int i = blockIdx.x * 256 + threadIdx.x;
  if (i >= n4) return;
  float4 v = ((const float4*)in)[i];
  unsigned int w0, w1;
  quant4(v, w0, w1);
  ((unsigned int*)q0)[i] = w0;
  ((unsigned int*)q1)[i] = w1;
}

// one block per codebook row: i8 split + row sum of squares
__global__ __launch_bounds__(256) void prep_cb_i8(const float* __restrict__ cb,
                                                  s8* __restrict__ q0, s8* __restrict__ q1,
                                                  float* __restrict__ c_sq) {
  long k = blockIdx.x;
  int t = threadIdx.x, lane = t & 63, wave = t >> 6;
  float4 v = ((const float4*)(cb + k * 1024))[t];
  unsigned int w0, w1;
  quant4(v, w0, w1);
  ((unsigned int*)(q0 + k * 1024))[t] = w0;
  ((unsigned int*)(q1 + k * 1024))[t] = w1;
  float ss = v.x * v.x + v.y * v.y + v.z * v.z + v.w * v.w;
#pragma unroll
  for (int o = 32; o; o >>= 1) ss += __shfl_xor(ss, o);
  __shared__ float sc[4];
  if (lane == 0) sc[wave] = ss;
  __syncthreads();
  if (t == 0) c_sq[k] = sc[0] + sc[1] + sc[2] + sc[3];
}

__global__ __launch_bounds__(256) void prep_bf16(const float* __restrict__ in,
                                                 u16* __restrict__ o, int n4) {
  int i = blockIdx.x * 256 + threadIdx.x;
  if (i >= n4) return;
  float4 v = ((const float4*)in)[i];
  ushort4 h;
  h.x = f2bf(v.x); h.y = f2bf(v.y); h.z = f2bf(v.z); h.w = f2bf(v.w);
  ((ushort4*)o)[i] = h;
}

// cbT[d][k] = bf16(cb[k][d]);  64x64 tiles
__global__ __launch_bounds__(256) void transpose_cb(const float* __restrict__ cb,
                                                    u16* __restrict__ cbT) {
  __shared__ u16 tt[64][65];
  long k0 = (long)blockIdx.x * 64, d0 = (long)blockIdx.y * 64;
  int t = threadIdx.x;
  int rr = t >> 4, cc = (t & 15) * 4;
#pragma unroll
  for (int p = 0; p < 4; ++p) {
    int r = rr + p * 16;
    float4 v = *(const float4*)(cb + (k0 + r) * 1024 + d0 + cc);
    tt[r][cc] = f2bf(v.x); tt[r][cc + 1] = f2bf(v.y);
    tt[r][cc + 2] = f2bf(v.z); tt[r][cc + 3] = f2bf(v.w);
  }
  __syncthreads();
#pragma unroll
  for (int p = 0; p < 4; ++p) {
    int d = rr + p * 16;
    ushort4 o;
    o.x = tt[cc][d]; o.y = tt[cc + 1][d]; o.z = tt[cc + 2][d]; o.w = tt[cc + 3][d];
    *(ushort4*)(cbT + (d0 + d) * 8192 + k0 + cc) = o;
  }
}

// one block per row of S [8192 floats]; writes q bf16 in-place over row start
__global__ __launch_bounds__(256) void softmax_rows(float* __restrict__ S) {
  long m = blockIdx.x;
  int t = threadIdx.x, lane = t & 63, wave = t >> 6;
  float* row = S + m * 8192;
  float4 v[8];
#pragma unroll
  for (int c = 0; c < 8; ++c) v[c] = ((const float4*)row)[c * 256 + t];
  float mx = -3.0e38f;
#pragma unroll
  for (int c = 0; c < 8; ++c)
    mx = fmaxf(mx, fmaxf(fmaxf(v[c].x, v[c].y), fmaxf(v[c].z, v[c].w)));
#pragma unroll
  for (int o = 32; o; o >>= 1) mx = fmaxf(mx, __shfl_xor(mx, o));
  __shared__ float sc[4];
  if (lane == 0) sc[wave] = mx;
  __syncthreads();
  mx = fmaxf(fmaxf(sc[0], sc[1]), fmaxf(sc[2], sc[3]));
  __syncthreads();
  float sum = 0.f;
#pragma unroll
  for (int c = 0; c < 8; ++c) {
    v[c].x = __expf(v[c].x - mx); v[c].y = __expf(v[c].y - mx);
    v[c].z = __expf(v[c].z - mx); v[c].w = __expf(v[c].w - mx);
    sum += v[c].x + v[c].y + v[c].z + v[c].w;
  }
#pragma unroll
  for (int o = 32; o; o >>= 1) sum += __shfl_xor(sum, o);
  if (lane == 0) sc[wave] = sum;
  __syncthreads();
  float rd = 1.f / (sc[0] + sc[1] + sc[2] + sc[3]);
  u16* q = (u16*)row;
#pragma unroll
  for (int c = 0; c < 8; ++c) {
    ushort4 o;
    o.x = f2bf(v[c].x * rd); o.y = f2bf(v[c].y * rd);
    o.z = f2bf(v[c].z * rd); o.w = f2bf(v[c].w * rd);
    ((ushort4*)q)[c * 256 + t] = o;
  }
}

// per chunk row: z_e = sum of 4 bf16 split-K partials (f32 out),
// then x = RMSNorm(h - z_e) * scale (bf16 out). h/z_e/x pre-offset to chunk.
__global__ __launch_bounds__(256) void reduce_rms(const u16* __restrict__ parts, long rows,
                                                  const float* __restrict__ h,
                                                  const float* __restrict__ scale,
                                                  float* __restrict__ z_e,
                                                  u16* __restrict__ x) {
  long m = blockIdx.x;
  int t = threadIdx.x, lane = t & 63, wave = t >> 6;
  long base = m * 1024 + t * 4;
  long sstride = rows * 1024;
  float4 ze = {0.f, 0.f, 0.f, 0.f};
#pragma unroll
  for (int s = 0; s < 4; ++s) {
    ushort4 p = *(const ushort4*)(parts + s * sstride + base);
    ze.x += bf2f(p.x); ze.y += bf2f(p.y); ze.z += bf2f(p.z); ze.w += bf2f(p.w);
  }
  *(float4*)(z_e + base) = ze;
  float4 hv = *(const float4*)(h + base);
  float4 r;
  r.x = hv.x - ze.x; r.y = hv.y - ze.y; r.z = hv.z - ze.z; r.w = hv.w - ze.w;
  float ss = r.x * r.x + r.y * r.y + r.z * r.z + r.w * r.w;
#pragma unroll
  for (int o = 32; o; o >>= 1) ss += __shfl_xor(ss, o);
  __shared__ float sc[4];
  if (lane == 0) sc[wave] = ss;
  __syncthreads();
  float tot = sc[0] + sc[1] + sc[2] + sc[3];
  float inv = 1.f / (sqrtf(tot * (1.f / 1024.f)) + 1e-8f);
  float4 s4 = *(const float4*)(scale + t * 4);
  ushort4 o;
  o.x = f2bf(r.x * inv * s4.x); o.y = f2bf(r.y * inv * s4.y);
  o.z = f2bf(r.z * inv * s4.z); o.w = f2bf(r.w * inv * s4.w);
  *(ushort4*)(x + base) = o;
}

extern "C" void kernel_launch(void* const* d_in, const int* in_sizes, int n_in,
                              void* d_out, int out_size, void* d_ws, size_t ws_size,
                              hipStream_t stream) {
  const float* h = (const float*)d_in[0];
  const float* cb = (const float*)d_in[1];
  const float* scale = (const float*)d_in[2];
  const float* W = (const float*)d_in[3];
  const float* b = (const float*)d_in[4];
  float* out = (float*)d_out;

  // ws layout: fixed buffers (~98 MB); tail = split-K partials (RC*8KB) + S chunk (RC*32KB)
  char* ws = (char*)d_ws;
  size_t off = 0;
  auto alloc = [&](size_t bytes) -> char* {
    char* p = ws + off;
    off = (off + bytes + 255) & ~(size_t)255;
    return p;
  };
  s8* h0 = (s8*)alloc(8192L * 1024);
  s8* h1 = (s8*)alloc(8192L * 1024);
  s8* c0 = (s8*)alloc(8192L * 1024);
  s8* c1 = (s8*)alloc(8192L * 1024);
  u16* cbT = (u16*)alloc(1024L * 8192 * 2);
  u16* Wbf = (u16*)alloc(1024L * 1024 * 2);
  float* c_sq = (float*)alloc(8192L * 4);
  float* z_e = (float*)alloc(8192L * 1024 * 4);
  u16* x = (u16*)alloc(8192L * 1024 * 2);

  // rows per chunk: each row needs 32768 B (S f32) + 8192 B (4 bf16 partials)
  long RC = 128;
  if (ws_size > off + 128 * 40960L) {
    long cap = (long)((ws_size - off) / 40960L);
    cap = (cap / 128) * 128;
    if (cap > RC) RC = cap;
    if (RC > 8192) RC = 8192;
  }
  u16* parts = (u16*)(ws + off);                        // [4][RC][1024] bf16
  float* S = (float*)(ws + off + (size_t)RC * 8192);    // [RC][8192] f32 (q bf16 in-place)

  prep_h_i8<<<8192, 256, 0, stream>>>(h, h0, h1, 2097152);
  prep_cb_i8<<<8192, 256, 0, stream>>>(cb, c0, c1, c_sq);
  prep_bf16<<<1024, 256, 0, stream>>>(W, Wbf, 262144);
  transpose_cb<<<dim3(128, 16), 256, 0, stream>>>(cb, cbT);

  for (long r0 = 0; r0 < 8192; r0 += RC) {
    long rows = 8192 - r0;
    if (rows > RC) rows = RC;
    // S = 2*h@cb^T - c_sq  via i8 split-2 (4 exact passes)
    gemm_s8<<<dim3(128, rows / 128), 256, 0, stream>>>(
        h0 + r0 * 1024, h1 + r0 * 1024, c0, c1, S, c_sq);
    // q = softmax(S) rows, bf16 in-place (row stride 16384 u16)
    softmax_rows<<<rows, 256, 0, stream>>>(S);
    // z_e partials: split-K=4 (span 2048), bf16 partial per z-slice
    gemm_bt<3><<<dim3(8, rows / 128, 4), 256, 0, stream>>>(
        (u16*)S, 16384L, cbT, 8192L,
        parts, 1024L, 2048, nullptr, nullptr, rows * 1024L);
    // z_e = sum(parts); x = RMSNorm(h - z_e)*scale
    reduce_rms<<<rows, 256, 0, stream>>>(parts, rows, h + r0 * 1024, scale,
                                         z_e + r0 * 1024, x + r0 * 1024);
  }

  // out = z_e + x @ W^T + b
  gemm_bt<2><<<dim3(8, 64), 256, 0, stream>>>(x, 1024L, Wbf, 1024L,
                                              out, 1024L, 1024, z_e, b, 0);
}

// Round 7
// 663.304 us; speedup vs baseline: 1.5980x; 1.5980x over previous
//
#include <hip/hip_runtime.h>

typedef unsigned short u16;
typedef signed char s8;
typedef __attribute__((ext_vector_type(8))) short bf16x8;
typedef __attribute__((ext_vector_type(4))) float f32x4;
typedef __attribute__((ext_vector_type(4))) int i32x4;

__device__ __forceinline__ u16 f2bf(float x) {
  unsigned int u = __float_as_uint(x);
  u = u + 0x7FFFu + ((u >> 16) & 1u);
  return (u16)(u >> 16);
}
__device__ __forceinline__ float bf2f(u16 v) {
  return __uint_as_float(((unsigned int)v) << 16);
}

typedef const __attribute__((address_space(1))) void gas_void;
typedef __attribute__((address_space(3))) void las_void;

__device__ __forceinline__ void gld_lds16(const void* g, void* l) {
  __builtin_amdgcn_global_load_lds((gas_void*)g, (las_void*)l, 16, 0, 0);
}

// ---------------- i8 logits GEMM: S = 2*h@cb^T - c_sq via split-2 i8 ----------------
// h = h0/16 + h1/4096 + eps, cb likewise. One fused K-sweep, 3 exact-i32 accumulator sets:
//   M = h0@c0, X = h0@c1 + h1@c0, Y = h1@c1;  S = M*2^-7 + X*2^-15 + Y*2^-23 - c_sq
// Block 128x64, 4 waves (2x2), wave tile 64x32, BK=128 (128B rows).
// LDS XOR-swizzle: stored byte = row*128 + (col16 ^ (row&7))*16; inverse applied on
// the global source (gld_lds dest stays linear), same XOR applied on ds_read.
__global__ __launch_bounds__(256) void gemm_s8(
    const s8* __restrict__ A0, const s8* __restrict__ A1,
    const s8* __restrict__ B0, const s8* __restrict__ B1,
    float* __restrict__ S, const float* __restrict__ c_sq) {
  __shared__ __align__(16) s8 lA0[128 * 128];
  __shared__ __align__(16) s8 lA1[128 * 128];
  __shared__ __align__(16) s8 lB0[64 * 128];
  __shared__ __align__(16) s8 lB1[64 * 128];
  int tid = threadIdx.x, wave = tid >> 6, lane = tid & 63;
  long bm = (long)blockIdx.y * 128, bn = (long)blockIdx.x * 64;
  int wm = (wave >> 1) * 64, wn = (wave & 1) * 32;
  int r15 = lane & 15, kg = lane >> 4;
  int srow = wave * 8 + (lane >> 3);                 // staging row within 32-row group
  int scol = ((lane & 7) ^ (lane >> 3)) * 16;        // inverse-swizzled source col (bytes)

  i32x4 accM[4][2], accX[4][2], accY[4][2];
#pragma unroll
  for (int i = 0; i < 4; ++i)
#pragma unroll
    for (int j = 0; j < 2; ++j) {
      accM[i][j] = (i32x4){0, 0, 0, 0};
      accX[i][j] = (i32x4){0, 0, 0, 0};
      accY[i][j] = (i32x4){0, 0, 0, 0};
    }

  const s8* a0p = A0 + bm * 1024;
  const s8* a1p = A1 + bm * 1024;
  const s8* b0p = B0 + bn * 1024;
  const s8* b1p = B1 + bn * 1024;

  for (int k0 = 0; k0 < 1024; k0 += 128) {
    __syncthreads();
#pragma unroll
    for (int c = 0; c < 4; ++c) {
      long go = (long)(c * 32 + srow) * 1024 + k0 + scol;
      gld_lds16(a0p + go, lA0 + c * 4096 + wave * 1024);
      gld_lds16(a1p + go, lA1 + c * 4096 + wave * 1024);
    }
#pragma unroll
    for (int c = 0; c < 2; ++c) {
      long go = (long)(c * 32 + srow) * 1024 + k0 + scol;
      gld_lds16(b0p + go, lB0 + c * 4096 + wave * 1024);
      gld_lds16(b1p + go, lB1 + c * 4096 + wave * 1024);
    }
    __syncthreads();
#pragma unroll
    for (int kk = 0; kk < 2; ++kk) {
      int cb = ((kk * 4 + kg) ^ (r15 & 7)) * 16;
      i32x4 b0f[2], b1f[2];
#pragma unroll
      for (int j = 0; j < 2; ++j) {
        b0f[j] = *(const i32x4*)&lB0[(wn + j * 16 + r15) * 128 + cb];
        b1f[j] = *(const i32x4*)&lB1[(wn + j * 16 + r15) * 128 + cb];
      }
#pragma unroll
      for (int i = 0; i < 4; ++i) {
        i32x4 a0f = *(const i32x4*)&lA0[(wm + i * 16 + r15) * 128 + cb];
        i32x4 a1f = *(const i32x4*)&lA1[(wm + i * 16 + r15) * 128 + cb];
#pragma unroll
        for (int j = 0; j < 2; ++j) {
          accM[i][j] = __builtin_amdgcn_mfma_i32_16x16x64_i8(a0f, b0f[j], accM[i][j], 0, 0, 0);
          accX[i][j] = __builtin_amdgcn_mfma_i32_16x16x64_i8(a0f, b1f[j], accX[i][j], 0, 0, 0);
          accX[i][j] = __builtin_amdgcn_mfma_i32_16x16x64_i8(a1f, b0f[j], accX[i][j], 0, 0, 0);
          accY[i][j] = __builtin_amdgcn_mfma_i32_16x16x64_i8(a1f, b1f[j], accY[i][j], 0, 0, 0);
        }
      }
    }
  }

  // C/D layout: col=lane&15, row=(lane>>4)*4+r
#pragma unroll
  for (int i = 0; i < 4; ++i) {
    long rg = bm + wm + i * 16 + kg * 4;
#pragma unroll
    for (int j = 0; j < 2; ++j) {
      long cg = bn + wn + j * 16 + r15;
      float csq = c_sq[cg];
      i32x4 m = accM[i][j], x = accX[i][j], y = accY[i][j];
#pragma unroll
      for (int r = 0; r < 4; ++r)
        S[(rg + r) * 8192 + cg] = (float)m[r] * 0.0078125f +
                                  (float)x[r] * 3.0517578125e-05f +
                                  (float)y[r] * 1.1920928955078125e-07f - csq;
    }
  }
}

// ---------------- bf16 GEMM, BK=64 (128B rows) + same XOR swizzle ----------------
// MODE 2: C = acc + aux0[m*ldc+n] + aux1[n]   (z_q, f32)
// MODE 3: split-K over blockIdx.z (span KSPAN), bf16 partials (z_e parts)
#define BM 128
#define BN 128
#define BK 64

// stage [128][64] bf16 tile (128B rows), swizzled storage
__device__ __forceinline__ void stage_tile(const u16* __restrict__ src, long lda,
                                           long row0, long k0, u16* ldst,
                                           int wave, int lane) {
  int srow = wave * 8 + (lane >> 3);
  int scol = ((lane & 7) ^ (lane >> 3)) * 8;  // u16 units
#pragma unroll
  for (int c = 0; c < 4; ++c) {
    const u16* g = src + (row0 + c * 32 + srow) * lda + k0 + scol;
    gld_lds16(g, ldst + c * 2048 + wave * 512);
  }
}

template <int MODE>
__global__ __launch_bounds__(256) void gemm_bt(
    const u16* __restrict__ A0, long lda,
    const u16* __restrict__ B0, long ldb,
    void* __restrict__ Cv, long ldc, int KSPAN,
    const float* __restrict__ aux0, const float* __restrict__ aux1, long zstride) {
  __shared__ __align__(16) u16 lA0[BM * BK];
  __shared__ __align__(16) u16 lB0[BN * BK];

  int tid = threadIdx.x;
  int wave = tid >> 6, lane = tid & 63;
  long bm = (long)blockIdx.y * BM, bn = (long)blockIdx.x * BN;
  int wm = (wave >> 1) * 64, wn = (wave & 1) * 64;
  int r15 = lane & 15, kg = lane >> 4;
  long kbase = 0;
  if constexpr (MODE == 3) kbase = (long)blockIdx.z * KSPAN;

  f32x4 acc[4][4];
#pragma unroll
  for (int i = 0; i < 4; ++i)
#pragma unroll
    for (int j = 0; j < 4; ++j) acc[i][j] = (f32x4){0.f, 0.f, 0.f, 0.f};

  for (int k0 = 0; k0 < KSPAN; k0 += BK) {
    __syncthreads();
    stage_tile(A0, lda, bm, kbase + k0, lA0, wave, lane);
    stage_tile(B0, ldb, bn, kbase + k0, lB0, wave, lane);
    __syncthreads();

#pragma unroll
    for (int kk = 0; kk < 2; ++kk) {
      int cu = ((kk * 4 + kg) ^ (r15 & 7)) * 8;  // u16 units
      bf16x8 ah[4], bh[4];
#pragma unroll
      for (int i = 0; i < 4; ++i) {
        ah[i] = *(const bf16x8*)&lA0[(wm + i * 16 + r15) * 64 + cu];
        bh[i] = *(const bf16x8*)&lB0[(wn + i * 16 + r15) * 64 + cu];
      }
#pragma unroll
      for (int i = 0; i < 4; ++i)
#pragma unroll
        for (int j = 0; j < 4; ++j)
          acc[i][j] = __builtin_amdgcn_mfma_f32_16x16x32_bf16(ah[i], bh[j], acc[i][j], 0, 0, 0);
    }
  }

#pragma unroll
  for (int i = 0; i < 4; ++i) {
    long rg = bm + wm + i * 16 + kg * 4;
#pragma unroll
    for (int j = 0; j < 4; ++j) {
      long cg = bn + wn + j * 16 + r15;
      f32x4 v = acc[i][j];
      if constexpr (MODE == 2) {
        float* C = (float*)Cv;
        float bb = aux1[cg];
#pragma unroll
        for (int r = 0; r < 4; ++r)
          C[(rg + r) * ldc + cg] = v[r] + aux0[(rg + r) * ldc + cg] + bb;
      } else {
        u16* P = (u16*)Cv + (long)blockIdx.z * zstride;
#pragma unroll
        for (int r = 0; r < 4; ++r) P[(rg + r) * ldc + cg] = f2bf(v[r]);
      }
    }
  }
}

// ---------------- prep kernels ----------------
__device__ __forceinline__ int quant2(float x) {
  // packed (q0, q1): q0 = round(x*16) in [-127,127]; r = x - q0/16 in [-1/32,1/32];
  // q1 = round(r*4096) clipped to [-127,127]
  float x0 = rintf(x * 16.f);
  x0 = fminf(fmaxf(x0, -127.f), 127.f);
  float x1 = rintf((x - x0 * 0.0625f) * 4096.f);
  x1 = fminf(fmaxf(x1, -127.f), 127.f);
  return ((int)x0 & 0xFF) | (((int)x1 & 0xFF) << 8);
}

__device__ __forceinline__ void quant4(float4 v, unsigned int& w0, unsigned int& w1) {
  int px = quant2(v.x), py = quant2(v.y), pz = quant2(v.z), pw = quant2(v.w);
  w0 = (unsigned int)((px & 0xFF) | ((py & 0xFF) << 8) | ((pz & 0xFF) << 16) |
                      ((pw & 0xFF) << 24));
  w1 = (unsigned int)(((px >> 8) & 0xFF) | (((py >> 8) & 0xFF) << 8) |
                      (((pz >> 8) & 0xFF) << 16) | (((pw >> 8) & 0xFF) << 24));
}

__global__ __launch_bounds__(256) void prep_h_i8(const float* __restrict__ in,
                                                 s8* __restrict__ q0, s8* __restrict__ q1,
                                                 int n4) {
  int i = blockIdx.x * 256 + threadIdx.x;
  if (i >= n4) return;
  float4 v = ((const float4*)in)[i];
  unsigned int w0, w1;
  quant4(v, w0, w1);
  ((unsigned int*)q0)[i] = w0;
  ((unsigned int*)q1)[i] = w1;
}

// one block per codebook row: i8 split + row sum of squares
__global__ __launch_bounds__(256) void prep_cb_i8(const float* __restrict__ cb,
                                                  s8* __restrict__ q0, s8* __restrict__ q1,
                                                  float* __restrict__ c_sq) {
  long k = blockIdx.x;
  int t = threadIdx.x, lane = t & 63, wave = t >> 6;
  float4 v = ((const float4*)(cb + k * 1024))[t];
  unsigned int w0, w1;
  quant4(v, w0, w1);
  ((unsigned int*)(q0 + k * 1024))[t] = w0;
  ((unsigned int*)(q1 + k * 1024))[t] = w1;
  float ss = v.x * v.x + v.y * v.y + v.z * v.z + v.w * v.w;
#pragma unroll
  for (int o = 32; o; o >>= 1) ss += __shfl_xor(ss, o);
  __shared__ float sc[4];
  if (lane == 0) sc[wave] = ss;
  __syncthreads();
  if (t == 0) c_sq[k] = sc[0] + sc[1] + sc[2] + sc[3];
}

__global__ __launch_bounds__(256) void prep_bf16(const float* __restrict__ in,
                                                 u16* __restrict__ o, int n4) {
  int i = blockIdx.x * 256 + threadIdx.x;
  if (i >= n4) return;
  float4 v = ((const float4*)in)[i];
  ushort4 h;
  h.x = f2bf(v.x); h.y = f2bf(v.y); h.z = f2bf(v.z); h.w = f2bf(v.w);
  ((ushort4*)o)[i] = h;
}

// cbT[d][k] = bf16(cb[k][d]);  64x64 tiles
__global__ __launch_bounds__(256) void transpose_cb(const float* __restrict__ cb,
                                                    u16* __restrict__ cbT) {
  __shared__ u16 tt[64][65];
  long k0 = (long)blockIdx.x * 64, d0 = (long)blockIdx.y * 64;
  int t = threadIdx.x;
  int rr = t >> 4, cc = (t & 15) * 4;
#pragma unroll
  for (int p = 0; p < 4; ++p) {
    int r = rr + p * 16;
    float4 v = *(const float4*)(cb + (k0 + r) * 1024 + d0 + cc);
    tt[r][cc] = f2bf(v.x); tt[r][cc + 1] = f2bf(v.y);
    tt[r][cc + 2] = f2bf(v.z); tt[r][cc + 3] = f2bf(v.w);
  }
  __syncthreads();
#pragma unroll
  for (int p = 0; p < 4; ++p) {
    int d = rr + p * 16;
    ushort4 o;
    o.x = tt[cc][d]; o.y = tt[cc + 1][d]; o.z = tt[cc + 2][d]; o.w = tt[cc + 3][d];
    *(ushort4*)(cbT + (d0 + d) * 8192 + k0 + cc) = o;
  }
}

// one block per row of S [8192 floats]; writes q bf16 in-place over row start
__global__ __launch_bounds__(256) void softmax_rows(float* __restrict__ S) {
  long m = blockIdx.x;
  int t = threadIdx.x, lane = t & 63, wave = t >> 6;
  float* row = S + m * 8192;
  float4 v[8];
#pragma unroll
  for (int c = 0; c < 8; ++c) v[c] = ((const float4*)row)[c * 256 + t];
  float mx = -3.0e38f;
#pragma unroll
  for (int c = 0; c < 8; ++c)
    mx = fmaxf(mx, fmaxf(fmaxf(v[c].x, v[c].y), fmaxf(v[c].z, v[c].w)));
#pragma unroll
  for (int o = 32; o; o >>= 1) mx = fmaxf(mx, __shfl_xor(mx, o));
  __shared__ float sc[4];
  if (lane == 0) sc[wave] = mx;
  __syncthreads();
  mx = fmaxf(fmaxf(sc[0], sc[1]), fmaxf(sc[2], sc[3]));
  __syncthreads();
  float sum = 0.f;
#pragma unroll
  for (int c = 0; c < 8; ++c) {
    v[c].x = __expf(v[c].x - mx); v[c].y = __expf(v[c].y - mx);
    v[c].z = __expf(v[c].z - mx); v[c].w = __expf(v[c].w - mx);
    sum += v[c].x + v[c].y + v[c].z + v[c].w;
  }
#pragma unroll
  for (int o = 32; o; o >>= 1) sum += __shfl_xor(sum, o);
  if (lane == 0) sc[wave] = sum;
  __syncthreads();
  float rd = 1.f / (sc[0] + sc[1] + sc[2] + sc[3]);
  u16* q = (u16*)row;
#pragma unroll
  for (int c = 0; c < 8; ++c) {
    ushort4 o;
    o.x = f2bf(v[c].x * rd); o.y = f2bf(v[c].y * rd);
    o.z = f2bf(v[c].z * rd); o.w = f2bf(v[c].w * rd);
    ((ushort4*)q)[c * 256 + t] = o;
  }
}

// per chunk row: z_e = sum of 4 bf16 split-K partials (f32 out),
// then x = RMSNorm(h - z_e) * scale (bf16 out). h/z_e/x pre-offset to chunk.
__global__ __launch_bounds__(256) void reduce_rms(const u16* __restrict__ parts, long rows,
                                                  const float* __restrict__ h,
                                                  const float* __restrict__ scale,
                                                  float* __restrict__ z_e,
                                                  u16* __restrict__ x) {
  long m = blockIdx.x;
  int t = threadIdx.x, lane = t & 63, wave = t >> 6;
  long base = m * 1024 + t * 4;
  long sstride = rows * 1024;
  float4 ze = {0.f, 0.f, 0.f, 0.f};
#pragma unroll
  for (int s = 0; s < 4; ++s) {
    ushort4 p = *(const ushort4*)(parts + s * sstride + base);
    ze.x += bf2f(p.x); ze.y += bf2f(p.y); ze.z += bf2f(p.z); ze.w += bf2f(p.w);
  }
  *(float4*)(z_e + base) = ze;
  float4 hv = *(const float4*)(h + base);
  float4 r;
  r.x = hv.x - ze.x; r.y = hv.y - ze.y; r.z = hv.z - ze.z; r.w = hv.w - ze.w;
  float ss = r.x * r.x + r.y * r.y + r.z * r.z + r.w * r.w;
#pragma unroll
  for (int o = 32; o; o >>= 1) ss += __shfl_xor(ss, o);
  __shared__ float sc[4];
  if (lane == 0) sc[wave] = ss;
  __syncthreads();
  float tot = sc[0] + sc[1] + sc[2] + sc[3];
  float inv = 1.f / (sqrtf(tot * (1.f / 1024.f)) + 1e-8f);
  float4 s4 = *(const float4*)(scale + t * 4);
  ushort4 o;
  o.x = f2bf(r.x * inv * s4.x); o.y = f2bf(r.y * inv * s4.y);
  o.z = f2bf(r.z * inv * s4.z); o.w = f2bf(r.w * inv * s4.w);
  *(ushort4*)(x + base) = o;
}

extern "C" void kernel_launch(void* const* d_in, const int* in_sizes, int n_in,
                              void* d_out, int out_size, void* d_ws, size_t ws_size,
                              hipStream_t stream) {
  const float* h = (const float*)d_in[0];
  const float* cb = (const float*)d_in[1];
  const float* scale = (const float*)d_in[2];
  const float* W = (const float*)d_in[3];
  const float* b = (const float*)d_in[4];
  float* out = (float*)d_out;

  // ws layout: fixed buffers (~98 MB); tail = split-K partials (RC*8KB) + S chunk (RC*32KB)
  char* ws = (char*)d_ws;
  size_t off = 0;
  auto alloc = [&](size_t bytes) -> char* {
    char* p = ws + off;
    off = (off + bytes + 255) & ~(size_t)255;
    return p;
  };
  s8* h0 = (s8*)alloc(8192L * 1024);
  s8* h1 = (s8*)alloc(8192L * 1024);
  s8* c0 = (s8*)alloc(8192L * 1024);
  s8* c1 = (s8*)alloc(8192L * 1024);
  u16* cbT = (u16*)alloc(1024L * 8192 * 2);
  u16* Wbf = (u16*)alloc(1024L * 1024 * 2);
  float* c_sq = (float*)alloc(8192L * 4);
  float* z_e = (float*)alloc(8192L * 1024 * 4);
  u16* x = (u16*)alloc(8192L * 1024 * 2);

  // rows per chunk: each row needs 32768 B (S f32) + 8192 B (4 bf16 partials)
  long RC = 128;
  if (ws_size > off + 128 * 40960L) {
    long cap = (long)((ws_size - off) / 40960L);
    cap = (cap / 128) * 128;
    if (cap > RC) RC = cap;
    if (RC > 8192) RC = 8192;
  }
  u16* parts = (u16*)(ws + off);                        // [4][RC][1024] bf16
  float* S = (float*)(ws + off + (size_t)RC * 8192);    // [RC][8192] f32 (q bf16 in-place)

  prep_h_i8<<<8192, 256, 0, stream>>>(h, h0, h1, 2097152);
  prep_cb_i8<<<8192, 256, 0, stream>>>(cb, c0, c1, c_sq);
  prep_bf16<<<1024, 256, 0, stream>>>(W, Wbf, 262144);
  transpose_cb<<<dim3(128, 16), 256, 0, stream>>>(cb, cbT);

  for (long r0 = 0; r0 < 8192; r0 += RC) {
    long rows = 8192 - r0;
    if (rows > RC) rows = RC;
    // S = 2*h@cb^T - c_sq  via i8 split-2, fused single K-sweep
    gemm_s8<<<dim3(128, rows / 128), 256, 0, stream>>>(
        h0 + r0 * 1024, h1 + r0 * 1024, c0, c1, S, c_sq);
    // q = softmax(S) rows, bf16 in-place (row stride 16384 u16)
    softmax_rows<<<rows, 256, 0, stream>>>(S);
    // z_e partials: split-K=4 (span 2048), bf16 partial per z-slice
    gemm_bt<3><<<dim3(8, rows / 128, 4), 256, 0, stream>>>(
        (u16*)S, 16384L, cbT, 8192L,
        parts, 1024L, 2048, nullptr, nullptr, rows * 1024L);
    // z_e = sum(parts); x = RMSNorm(h - z_e)*scale
    reduce_rms<<<rows, 256, 0, stream>>>(parts, rows, h + r0 * 1024, scale,
                                         z_e + r0 * 1024, x + r0 * 1024);
  }

  // out = z_e + x @ W^T + b
  gemm_bt<2><<<dim3(8, 64), 256, 0, stream>>>(x, 1024L, Wbf, 1024L,
                                              out, 1024L, 1024, z_e, b, 0);
}